// Round 4
// baseline (404.378 us; speedup 1.0000x reference)
//
#include <hip/hip_runtime.h>

// NonLocalBlock: B=2, C=256, N=D*H*W=6272, mid=128.
// R4 = R0 structure + T14 async-STAGE split (issue-early / write-late):
//  - revert KS split (R3: 2x occupancy, 24% LOWER throughput - lockstep
//    phases mean TLP can't hide the staging latency; ~75% of cycles were
//    exposed vmcnt/barrier stall).
//  - prefetch tile kt+1's K/V into REGISTERS right after tile kt is visible
//    in LDS; global latency hides under tile kt's QK+softmax+PV; the
//    ds_write of kt+1 lands after the next barrier (waitcnt free by then).
//  - keep R3's 68-pad (stride 136 B -> 2-way LDS conflict = free;
//    conflicts 1.23M -> 188K measured).
//  - grid (NN/32, BB) = 392 blocks, block 128 (2 waves), LDS 39680 B
//    (4 blocks/CU cap), launch_bounds(128,2) -> VGPR cap 256 (~190 used).
// ws: Qg f16 | Kg f16 | VtG f16 | attnW f32 = 16.05 MB (known-good R0 size).

#define BB  2
#define CC  256
#define NN  6272
#define MID 128
#define NT  (NN / 64)

typedef _Float16 half4_t __attribute__((ext_vector_type(4)));
typedef _Float16 half8_t __attribute__((ext_vector_type(8)));
typedef float    floatx16 __attribute__((ext_vector_type(16)));

__device__ __forceinline__ void fma4(float4& a, const float4 v, const float s) {
    a.x += v.x * s; a.y += v.y * s; a.z += v.z * s; a.w += v.w * s;
}
__device__ __forceinline__ float dot4(const float4 a, const float4 b) {
    return a.x * b.x + a.y * b.y + a.z * b.z + a.w * b.w;
}

// ---------------------------------------------------------------------------
// Projection: e_pj[n][m] = dot(w_pj[m,:], x[b,:,n]) + bias.
// pj 0 -> Qg f16 [b][n][128]; pj 1 -> Kg f16 [b][n][128]; pj 2 -> VtG f16 [b][128][n].
// grid (NN/64, 3, BB), block 256.
// ---------------------------------------------------------------------------
__global__ __launch_bounds__(256, 2) void proj_kernel(
    const float* __restrict__ x,
    const float* __restrict__ w1, const float* __restrict__ bi1,
    const float* __restrict__ w2, const float* __restrict__ bi2,
    const float* __restrict__ w3, const float* __restrict__ bi3,
    _Float16* __restrict__ Qg, _Float16* __restrict__ Kg, _Float16* __restrict__ VtG)
{
    const int t  = threadIdx.x;
    const int n0 = blockIdx.x * 64;
    const int pj = blockIdx.y;
    const int b  = blockIdx.z;
    const float* w  = (pj == 0) ? w1 : (pj == 1) ? w2 : w3;
    const float* bi = (pj == 0) ? bi1 : (pj == 1) ? bi2 : bi3;

    __shared__ float xs[CC * 68];
    {
        const float* xb = x + (size_t)b * CC * NN;
        for (int r = t; r < CC * 16; r += 256) {
            int c = r >> 4, j = (r & 15) << 2;
            float4 v = *(const float4*)(xb + (size_t)c * NN + n0 + j);
            *(float4*)&xs[c * 68 + j] = v;
        }
    }
    __syncthreads();

    const int n4 = (t & 15) << 2;   // 4 consecutive n per thread
    const int m0 = (t >> 4) << 3;   // 8 m-rows per thread
    float4 acc4[8];
    #pragma unroll
    for (int k = 0; k < 8; ++k) acc4[k] = make_float4(0.f, 0.f, 0.f, 0.f);

    for (int cc = 0; cc < CC; cc += 4) {
        float4 xv[4];
        #pragma unroll
        for (int u = 0; u < 4; ++u)
            xv[u] = *(const float4*)&xs[(cc + u) * 68 + n4];
        #pragma unroll
        for (int k = 0; k < 8; ++k) {
            float4 wq = *(const float4*)(w + (size_t)(m0 + k) * CC + cc);
            fma4(acc4[k], xv[0], wq.x);
            fma4(acc4[k], xv[1], wq.y);
            fma4(acc4[k], xv[2], wq.z);
            fma4(acc4[k], xv[3], wq.w);
        }
    }

    const float* af = (const float*)acc4;   // af[k*4 + i], i = n-sub, k = m-sub
    float bb[8];
    #pragma unroll
    for (int k = 0; k < 8; ++k) bb[k] = bi[m0 + k];

    if (pj < 2) {
        _Float16* eo = ((pj == 0) ? Qg : Kg) + (size_t)b * NN * MID;
        #pragma unroll
        for (int i = 0; i < 4; ++i) {
            half8_t h;
            #pragma unroll
            for (int k = 0; k < 8; ++k) h[k] = (_Float16)(af[k * 4 + i] + bb[k]);
            *(half8_t*)(eo + (size_t)(n0 + n4 + i) * MID + m0) = h;
        }
    } else {
        _Float16* eo = VtG + (size_t)b * MID * NN;
        #pragma unroll
        for (int k = 0; k < 8; ++k) {
            half4_t h;
            #pragma unroll
            for (int i = 0; i < 4; ++i) h[i] = (_Float16)(af[k * 4 + i] + bb[k]);
            *(half4_t*)(eo + (size_t)(m0 + k) * NN + n0 + n4) = h;
        }
    }
}

// ---------------------------------------------------------------------------
// Flash attention, f16 MFMA. grid (NN/32, BB), block 128 (2 waves).
// Wave w owns k'-half w of each 64-key tile; independent (m,l,O); end merge.
// T14 pipeline per tile: [barrier] ds_write(regs=tile kt) [barrier]
//   issue global loads tile kt+1 -> regs ; compute kt (QK, softmax, PV).
// S^T tile: D[k'][q]: col q = lane&31, row k' = (reg&3)+8*(reg>>2)+4*(lane>>5).
// LDS (39680 B): Ks [64][136] f16 | Vt [128][68] f16 | Pt [32][68] f16 |
//   stats 128 f32. Obuf [32][132] f32 aliases Ks for the end merge.
// ---------------------------------------------------------------------------
__global__ __launch_bounds__(128, 2) void attn_kernel(
    const _Float16* __restrict__ Qg, const _Float16* __restrict__ Kg,
    const _Float16* __restrict__ VtG, float* __restrict__ attnW)
{
    const int t    = threadIdx.x;
    const int lane = t & 63;
    const int wave = t >> 6;        // k'-half
    const int l31  = lane & 31;
    const int l5   = lane >> 5;
    const int q0   = blockIdx.x * 32;
    const int b    = blockIdx.y;

    __shared__ __align__(16) char lds[39680];
    _Float16* Ks = (_Float16*)lds;                       // 64*136 halfs
    _Float16* Vt = (_Float16*)(lds + 17408);             // 128*68 halfs
    _Float16* Pt = (_Float16*)(lds + 34816);             // 32*68 halfs
    float* stats = (float*)(lds + 39168);                // 128 f32
    float* Obuf  = (float*)lds;                          // 32*132 f32 (alias Ks)

    const _Float16* Qb = Qg + ((size_t)b * NN + q0) * MID;
    const _Float16* Kb = Kg + (size_t)b * NN * MID;
    const _Float16* Vb = VtG + (size_t)b * MID * NN;

    // Q B-frags: loop-invariant, pinned in registers.
    half8_t qf[8];
    #pragma unroll
    for (int ds = 0; ds < 8; ++ds)
        qf[ds] = *(const half8_t*)(Qb + (size_t)l31 * MID + ds * 16 + l5 * 8);

    floatx16 o[4];
    #pragma unroll
    for (int dt = 0; dt < 4; ++dt)
        #pragma unroll
        for (int j = 0; j < 16; ++j) o[dt][j] = 0.f;
    float m_run = -3.0e38f, l_run = 0.f;

    // Per-thread staging geometry (c = it*128 + t decomposed):
    const int kr   = t >> 4,  koff = (t & 15) * 8;   // K row = it*8 + kr
    const int vd   = t >> 3,  voff = (t & 7) * 8;    // V d   = it*16 + vd
    half8_t kreg[8], vreg[8];

    auto load_tile = [&](int nk) {
        #pragma unroll
        for (int it = 0; it < 8; ++it)
            kreg[it] = *(const half8_t*)(Kb + (size_t)(nk + it * 8 + kr) * MID + koff);
        #pragma unroll
        for (int it = 0; it < 8; ++it)
            vreg[it] = *(const half8_t*)(Vb + (size_t)(it * 16 + vd) * NN + nk + voff);
    };
    load_tile(0);   // prologue: tile 0 -> regs

    for (int kt = 0; kt < NT; ++kt) {
        const int nk = kt * 64;
        __syncthreads();   // everyone done READING the previous tile's LDS
        #pragma unroll
        for (int it = 0; it < 8; ++it)
            *(half8_t*)(Ks + (it * 8 + kr) * 136 + koff) = kreg[it];
        #pragma unroll
        for (int it = 0; it < 8; ++it)
            *(half8_t*)(Vt + (it * 16 + vd) * 68 + voff) = vreg[it];
        __syncthreads();   // tile kt visible to both waves

        // ---- T14: issue next tile's global loads NOW; they complete under
        //      the compute below and are consumed by next iter's ds_write ----
        load_tile(kt + 1 < NT ? nk + 64 : nk);

        // ---- S^T = K . Q^T over the wave's 32-k' strip ----
        floatx16 s;
        #pragma unroll
        for (int j = 0; j < 16; ++j) s[j] = 0.f;
        const _Float16* krow = Ks + (wave * 32 + l31) * 136 + l5 * 8;
        #pragma unroll
        for (int ds = 0; ds < 8; ++ds)
            s = __builtin_amdgcn_mfma_f32_32x32x16_f16(
                    *(const half8_t*)(krow + ds * 16), qf[ds], s, 0, 0, 0);

        // ---- online softmax (per lane: one q column, 16 of 32 k' rows) ----
        float tmax = s[0];
        #pragma unroll
        for (int j = 1; j < 16; ++j) tmax = fmaxf(tmax, s[j]);
        tmax = fmaxf(tmax, __shfl_xor(tmax, 32));
        const float m_new = fmaxf(m_run, tmax);
        const float alpha = __expf(m_run - m_new);
        m_run = m_new;

        float psum = 0.f;
        _Float16* prow = Pt + l31 * 68 + wave * 32 + 4 * l5;
        #pragma unroll
        for (int g = 0; g < 4; ++g) {
            float p0 = __expf(s[4 * g + 0] - m_new);
            float p1 = __expf(s[4 * g + 1] - m_new);
            float p2 = __expf(s[4 * g + 2] - m_new);
            float p3 = __expf(s[4 * g + 3] - m_new);
            psum += (p0 + p1) + (p2 + p3);
            half4_t h;
            h[0] = (_Float16)p0; h[1] = (_Float16)p1;
            h[2] = (_Float16)p2; h[3] = (_Float16)p3;
            *(half4_t*)(prow + 8 * g) = h;   // k' = wave*32 + 8g + 4*l5 + {0..3}
        }
        psum += __shfl_xor(psum, 32);
        l_run = l_run * alpha + psum;

        #pragma unroll
        for (int dt = 0; dt < 4; ++dt)
            #pragma unroll
            for (int j = 0; j < 16; ++j) o[dt][j] *= alpha;

        // Own-wave cross-lane LDS dependency (lane l reads lane l^32's Pt
        // writes): drain lgkmcnt, no block barrier needed (quadrants disjoint).
        __builtin_amdgcn_s_waitcnt(0xC07F);

        // ---- O^T += V^T . P^T over the wave's 32-kk strip ----
        #pragma unroll
        for (int ks = 0; ks < 2; ++ks) {
            half8_t pf = *(const half8_t*)(Pt + l31 * 68 + wave * 32 + ks * 16 + l5 * 8);
            const _Float16* vcol = Vt + wave * 32 + ks * 16 + l5 * 8;
            #pragma unroll
            for (int dt = 0; dt < 4; ++dt)
                o[dt] = __builtin_amdgcn_mfma_f32_32x32x16_f16(
                            *(const half8_t*)(vcol + (dt * 32 + l31) * 68), pf,
                            o[dt], 0, 0, 0);
        }
    }

    // ---- merge the two k'-half partials, normalize, store ----
    __syncthreads();   // all waves done with LDS tiles (Obuf aliases Ks)
    if (l5 == 0) {
        stats[wave * 64 + l31]      = m_run;
        stats[wave * 64 + 32 + l31] = l_run;
    }
    __syncthreads();
    const float m_o  = stats[(1 ^ wave) * 64 + l31];
    const float l_o  = stats[(1 ^ wave) * 64 + 32 + l31];
    const float m_st = fmaxf(m_run, m_o);
    const float sc   = __expf(m_run - m_st);
    const float l_st = l_run * sc + l_o * __expf(m_o - m_st);
    const float inv  = 1.0f / l_st;

    if (wave == 1) {
        #pragma unroll
        for (int dt = 0; dt < 4; ++dt)
            #pragma unroll
            for (int j = 0; j < 16; ++j) {
                int d = dt * 32 + (j & 3) + 8 * (j >> 2) + 4 * l5;
                Obuf[l31 * 132 + d] = o[dt][j] * sc;
            }
    }
    __syncthreads();
    if (wave == 0) {
        #pragma unroll
        for (int dt = 0; dt < 4; ++dt)
            #pragma unroll
            for (int j = 0; j < 16; ++j) {
                int d = dt * 32 + (j & 3) + 8 * (j >> 2) + 4 * l5;
                Obuf[l31 * 132 + d] = (Obuf[l31 * 132 + d] + o[dt][j] * sc) * inv;
            }
    }
    __syncthreads();
    #pragma unroll
    for (int it = 0; it < 8; ++it) {
        int c = it * 128 + t;
        int q = c >> 5, off = (c & 31) * 4;
        *(float4*)(attnW + ((size_t)b * NN + q0 + q) * MID + off) =
            *(const float4*)(Obuf + q * 132 + off);
    }
}

// ---------------------------------------------------------------------------
// Epilogue: out[b][c][n] = x + w4 @ attn^T + b4. grid (NN/64, BB), block 256.
// ---------------------------------------------------------------------------
__global__ __launch_bounds__(256, 2) void epi_kernel(
    const float* __restrict__ attnW, const float* __restrict__ w4,
    const float* __restrict__ b4, const float* __restrict__ x,
    float* __restrict__ out)
{
    const int t  = threadIdx.x;
    const int n0 = blockIdx.x * 64;
    const int b  = blockIdx.y;

    __shared__ float as[64 * 132];
    for (int r = t; r < 64 * 32; r += 256) {
        int q = r >> 5, g = r & 31;
        float4 v = *(const float4*)(attnW + ((size_t)b * NN + (n0 + q)) * MID + (g << 2));
        *(float4*)&as[q * 132 + (g << 2)] = v;
    }
    __syncthreads();

    const int n4 = (t & 15) << 2;
    const int c0 = (t >> 4) << 4;
    float4 accE[16];
    #pragma unroll
    for (int k = 0; k < 16; ++k) accE[k] = make_float4(0.f, 0.f, 0.f, 0.f);

    for (int ms = 0; ms < 32; ++ms) {
        float4 av[4];
        #pragma unroll
        for (int i = 0; i < 4; ++i)
            av[i] = *(const float4*)&as[(n4 + i) * 132 + (ms << 2)];
        #pragma unroll
        for (int k = 0; k < 16; ++k) {
            float4 wq = *(const float4*)(w4 + (size_t)(c0 + k) * MID + (ms << 2));
            accE[k].x += dot4(av[0], wq);
            accE[k].y += dot4(av[1], wq);
            accE[k].z += dot4(av[2], wq);
            accE[k].w += dot4(av[3], wq);
        }
    }

    #pragma unroll
    for (int k = 0; k < 16; ++k) {
        const int c = c0 + k;
        const float bv = b4[c];
        const size_t off = ((size_t)b * CC + c) * NN + n0 + n4;
        float4 xr = *(const float4*)(x + off);
        float4 r;
        r.x = accE[k].x + bv + xr.x;
        r.y = accE[k].y + bv + xr.y;
        r.z = accE[k].z + bv + xr.z;
        r.w = accE[k].w + bv + xr.w;
        *(float4*)(out + off) = r;
    }
}

extern "C" void kernel_launch(void* const* d_in, const int* in_sizes, int n_in,
                              void* d_out, int out_size, void* d_ws, size_t ws_size,
                              hipStream_t stream)
{
    const float* x  = (const float*)d_in[0];
    const float* w1 = (const float*)d_in[1];
    const float* b1 = (const float*)d_in[2];
    const float* w2 = (const float*)d_in[3];
    const float* b2 = (const float*)d_in[4];
    const float* w3 = (const float*)d_in[5];
    const float* b3 = (const float*)d_in[6];
    const float* w4 = (const float*)d_in[7];
    const float* b4 = (const float*)d_in[8];
    float* out = (float*)d_out;

    // ws: Qg f16 [B][N][128] | Kg f16 [B][N][128] | VtG f16 [B][128][N] | attnW f32 [B][N][128]
    _Float16* Qg  = (_Float16*)d_ws;
    _Float16* Kg  = Qg + (size_t)BB * NN * MID;
    _Float16* VtG = Kg + (size_t)BB * NN * MID;
    float* attnW  = (float*)(VtG + (size_t)BB * NN * MID);

    proj_kernel<<<dim3(NN / 64, 3, BB), 256, 0, stream>>>(x, w1, b1, w2, b2, w3, b3, Qg, Kg, VtG);
    attn_kernel<<<dim3(NN / 32, BB), 128, 0, stream>>>(Qg, Kg, VtG, attnW);
    epi_kernel<<<dim3(NN / 64, BB), 256, 0, stream>>>(attnW, w4, b4, x, out);
}

// Round 5
// 328.588 us; speedup vs baseline: 1.2307x; 1.2307x over previous
//
#include <hip/hip_runtime.h>

// NonLocalBlock: B=2, C=256, N=D*H*W=6272, mid=128.
// R5: q-split 4-wave attention block (QB=128) + KS=4 flash-decode.
//  - The measured cost in R0/R3/R4 is the stage:compute ratio: 32KB staged
//    per 64-key tile fed only 32 MFMAs. Here 4 waves own DIFFERENT 32-q-row
//    strips and share the staged K/V tile -> 128 MFMAs per staged tile (4x),
//    and the cross-wave (m,l,O) merge disappears (waves independent in q).
//  - KS=4 flash-decode (R2b-proven mechanics): unnormalized f16 partial O in
//    d_out (exactly out_size), (m,l) to MLg; comb merges -> f16 attnW; f16 epi.
//  - defer-max (THR=0, exact); 68/136-pad LDS strides (2-way = free).
//  - grid (49, KS, BB)=392 blocks x 256 thr; LDS 52224 B; launch_bounds(256,2).
// ws: Qg f16 | Kg f16 | VtG f16 | attnW f16 | MLg f32 = 13.25 MB.

#define BB  2
#define CC  256
#define NN  6272
#define MID 128
#define KS  4
#define QB  128
#define NT  (NN / 64)

typedef _Float16 half4_t __attribute__((ext_vector_type(4)));
typedef _Float16 half8_t __attribute__((ext_vector_type(8)));
typedef float    floatx16 __attribute__((ext_vector_type(16)));

__device__ __forceinline__ void fma4(float4& a, const float4 v, const float s) {
    a.x += v.x * s; a.y += v.y * s; a.z += v.z * s; a.w += v.w * s;
}
__device__ __forceinline__ float dot4(const float4 a, const float4 b) {
    return a.x * b.x + a.y * b.y + a.z * b.z + a.w * b.w;
}

// ---------------------------------------------------------------------------
// Projection: e_pj[n][m] = dot(w_pj[m,:], x[b,:,n]) + bias.
// pj 0 -> Qg f16 [b][n][128]; pj 1 -> Kg f16 [b][n][128]; pj 2 -> VtG f16 [b][128][n].
// grid (NN/64, 3, BB), block 256.
// ---------------------------------------------------------------------------
__global__ __launch_bounds__(256, 2) void proj_kernel(
    const float* __restrict__ x,
    const float* __restrict__ w1, const float* __restrict__ bi1,
    const float* __restrict__ w2, const float* __restrict__ bi2,
    const float* __restrict__ w3, const float* __restrict__ bi3,
    _Float16* __restrict__ Qg, _Float16* __restrict__ Kg, _Float16* __restrict__ VtG)
{
    const int t  = threadIdx.x;
    const int n0 = blockIdx.x * 64;
    const int pj = blockIdx.y;
    const int b  = blockIdx.z;
    const float* w  = (pj == 0) ? w1 : (pj == 1) ? w2 : w3;
    const float* bi = (pj == 0) ? bi1 : (pj == 1) ? bi2 : bi3;

    __shared__ float xs[CC * 68];
    {
        const float* xb = x + (size_t)b * CC * NN;
        for (int r = t; r < CC * 16; r += 256) {
            int c = r >> 4, j = (r & 15) << 2;
            float4 v = *(const float4*)(xb + (size_t)c * NN + n0 + j);
            *(float4*)&xs[c * 68 + j] = v;
        }
    }
    __syncthreads();

    const int n4 = (t & 15) << 2;   // 4 consecutive n per thread
    const int m0 = (t >> 4) << 3;   // 8 m-rows per thread
    float4 acc4[8];
    #pragma unroll
    for (int k = 0; k < 8; ++k) acc4[k] = make_float4(0.f, 0.f, 0.f, 0.f);

    for (int cc = 0; cc < CC; cc += 4) {
        float4 xv[4];
        #pragma unroll
        for (int u = 0; u < 4; ++u)
            xv[u] = *(const float4*)&xs[(cc + u) * 68 + n4];
        #pragma unroll
        for (int k = 0; k < 8; ++k) {
            float4 wq = *(const float4*)(w + (size_t)(m0 + k) * CC + cc);
            fma4(acc4[k], xv[0], wq.x);
            fma4(acc4[k], xv[1], wq.y);
            fma4(acc4[k], xv[2], wq.z);
            fma4(acc4[k], xv[3], wq.w);
        }
    }

    const float* af = (const float*)acc4;   // af[k*4 + i], i = n-sub, k = m-sub
    float bb[8];
    #pragma unroll
    for (int k = 0; k < 8; ++k) bb[k] = bi[m0 + k];

    if (pj < 2) {
        _Float16* eo = ((pj == 0) ? Qg : Kg) + (size_t)b * NN * MID;
        #pragma unroll
        for (int i = 0; i < 4; ++i) {
            half8_t h;
            #pragma unroll
            for (int k = 0; k < 8; ++k) h[k] = (_Float16)(af[k * 4 + i] + bb[k]);
            *(half8_t*)(eo + (size_t)(n0 + n4 + i) * MID + m0) = h;
        }
    } else {
        _Float16* eo = VtG + (size_t)b * MID * NN;
        #pragma unroll
        for (int k = 0; k < 8; ++k) {
            half4_t h;
            #pragma unroll
            for (int i = 0; i < 4; ++i) h[i] = (_Float16)(af[k * 4 + i] + bb[k]);
            *(half4_t*)(eo + (size_t)(m0 + k) * NN + n0 + n4) = h;
        }
    }
}

// ---------------------------------------------------------------------------
// Flash attention partial, f16 MFMA, q-split. grid (NN/QB, KS, BB), block 256
// (4 waves). Wave w owns q-rows [q0 + w*32, +32); all waves share the staged
// K/V tile (64 keys). Per tile per wave: 2 QK^T strips (k' 0..31, 32..63) +
// online softmax over 64 k' + PV with K=64. No cross-wave merge (q-disjoint).
// Partial O stored UNNORMALIZED f16 to Opart[b][sp] (= d_out), (m,l) to MLg.
// S^T strip: col q = lane&31, row k' = (reg&3)+8*(reg>>2)+4*(lane>>5).
// LDS (52224 B): Ks [64][136] h (17408) | Vt [128][68] h (17408) |
//   Pt[w] [32][68] h (4352 x4). Osh [128][136] h aliases Ks+Vt for store.
// ---------------------------------------------------------------------------
__global__ __launch_bounds__(256, 2) void attn_kernel(
    const _Float16* __restrict__ Qg, const _Float16* __restrict__ Kg,
    const _Float16* __restrict__ VtG, _Float16* __restrict__ Opart,
    float* __restrict__ MLg)
{
    const int t    = threadIdx.x;
    const int lane = t & 63;
    const int wave = t >> 6;        // q-strip owner (0..3)
    const int l31  = lane & 31;
    const int l5   = lane >> 5;
    const int q0   = blockIdx.x * QB;
    const int sp   = blockIdx.y;
    const int b    = blockIdx.z;
    const int kt0  = (NT * sp) / KS;
    const int kt1  = (NT * (sp + 1)) / KS;

    __shared__ __align__(16) char lds[52224];
    _Float16* Ks  = (_Float16*)lds;                          // 64*136 halfs
    _Float16* Vt  = (_Float16*)(lds + 17408);                // 128*68 halfs
    _Float16* Pt  = (_Float16*)(lds + 34816 + wave * 4352);  // [32][68] per wave
    _Float16* Osh = (_Float16*)lds;                          // [128][136] h alias

    const _Float16* Qb = Qg + ((size_t)b * NN + q0 + wave * 32) * MID;
    const _Float16* Kb = Kg + (size_t)b * NN * MID;
    const _Float16* Vb = VtG + (size_t)b * MID * NN;

    // Q B-frags: loop-invariant, pinned in registers (wave's own 32 q-rows).
    half8_t qf[8];
    #pragma unroll
    for (int ds = 0; ds < 8; ++ds)
        qf[ds] = *(const half8_t*)(Qb + (size_t)l31 * MID + ds * 16 + l5 * 8);

    floatx16 o[4];
    #pragma unroll
    for (int dt = 0; dt < 4; ++dt)
        #pragma unroll
        for (int j = 0; j < 16; ++j) o[dt][j] = 0.f;
    float m_run = -3.0e38f, l_run = 0.f;

    for (int kt = kt0; kt < kt1; ++kt) {
        const int nk = kt * 64;
        // ---- stage K tile [64][136] and V^T tile [128][68], 256 threads ----
        #pragma unroll
        for (int it = 0; it < 4; ++it) {
            int c = it * 256 + t;
            int r = c >> 4, off = (c & 15) * 8;
            *(half8_t*)(Ks + r * 136 + off) =
                *(const half8_t*)(Kb + (size_t)(nk + r) * MID + off);
        }
        #pragma unroll
        for (int it = 0; it < 4; ++it) {
            int c = it * 256 + t;
            int d = c >> 3, off = (c & 7) * 8;
            *(half8_t*)(Vt + d * 68 + off) =
                *(const half8_t*)(Vb + (size_t)d * NN + nk + off);
        }
        __syncthreads();

        // ---- S^T strips: s0 = K[0:32].Q^T, s1 = K[32:64].Q^T ----
        floatx16 s0, s1;
        #pragma unroll
        for (int j = 0; j < 16; ++j) { s0[j] = 0.f; s1[j] = 0.f; }
        const _Float16* krow0 = Ks + l31 * 136 + l5 * 8;
        const _Float16* krow1 = Ks + (32 + l31) * 136 + l5 * 8;
        #pragma unroll
        for (int ds = 0; ds < 8; ++ds) {
            s0 = __builtin_amdgcn_mfma_f32_32x32x16_f16(
                     *(const half8_t*)(krow0 + ds * 16), qf[ds], s0, 0, 0, 0);
            s1 = __builtin_amdgcn_mfma_f32_32x32x16_f16(
                     *(const half8_t*)(krow1 + ds * 16), qf[ds], s1, 0, 0, 0);
        }

        // ---- online softmax over 64 k' (lane: one q col, 32 of 64 rows) ----
        float tmax = fmaxf(s0[0], s1[0]);
        #pragma unroll
        for (int j = 1; j < 16; ++j) tmax = fmaxf(tmax, fmaxf(s0[j], s1[j]));
        tmax = fmaxf(tmax, __shfl_xor(tmax, 32));

        // defer-max (THR=0): skip rescale when no lane's max grew (exact).
        if (!__all(tmax <= m_run)) {
            const float m_new = fmaxf(m_run, tmax);
            const float alpha = __expf(m_run - m_new);
            m_run = m_new;
            l_run *= alpha;
            #pragma unroll
            for (int dt = 0; dt < 4; ++dt)
                #pragma unroll
                for (int j = 0; j < 16; ++j) o[dt][j] *= alpha;
        }

        float psum = 0.f;
        _Float16* prow = Pt + l31 * 68 + 4 * l5;
        #pragma unroll
        for (int g = 0; g < 4; ++g) {
            float p0 = __expf(s0[4 * g + 0] - m_run);
            float p1 = __expf(s0[4 * g + 1] - m_run);
            float p2 = __expf(s0[4 * g + 2] - m_run);
            float p3 = __expf(s0[4 * g + 3] - m_run);
            psum += (p0 + p1) + (p2 + p3);
            half4_t h;
            h[0] = (_Float16)p0; h[1] = (_Float16)p1;
            h[2] = (_Float16)p2; h[3] = (_Float16)p3;
            *(half4_t*)(prow + 8 * g) = h;          // k' = 8g + 4*l5 + {0..3}
        }
        #pragma unroll
        for (int g = 0; g < 4; ++g) {
            float p0 = __expf(s1[4 * g + 0] - m_run);
            float p1 = __expf(s1[4 * g + 1] - m_run);
            float p2 = __expf(s1[4 * g + 2] - m_run);
            float p3 = __expf(s1[4 * g + 3] - m_run);
            psum += (p0 + p1) + (p2 + p3);
            half4_t h;
            h[0] = (_Float16)p0; h[1] = (_Float16)p1;
            h[2] = (_Float16)p2; h[3] = (_Float16)p3;
            *(half4_t*)(prow + 32 + 8 * g) = h;     // k' = 32 + 8g + 4*l5 + {0..3}
        }
        psum += __shfl_xor(psum, 32);
        l_run += psum;

        // Own-wave cross-lane LDS dependency (Pt is per-wave): drain lgkmcnt.
        __builtin_amdgcn_s_waitcnt(0xC07F);

        // ---- O^T += V^T . P^T, K = 64 (4 k-slices) ----
        #pragma unroll
        for (int ks = 0; ks < 4; ++ks) {
            half8_t pf = *(const half8_t*)(Pt + l31 * 68 + ks * 16 + l5 * 8);
            const _Float16* vcol = Vt + ks * 16 + l5 * 8;
            #pragma unroll
            for (int dt = 0; dt < 4; ++dt)
                o[dt] = __builtin_amdgcn_mfma_f32_32x32x16_f16(
                            *(const half8_t*)(vcol + (dt * 32 + l31) * 68), pf,
                            o[dt], 0, 0, 0);
        }
        __syncthreads();
    }

    // ---- per-row (m,l) out; transpose O via LDS; store UNNORMALIZED f16 ----
    if (l5 == 0) {
        float* mlb = MLg + ((size_t)(b * KS + sp) * 2) * NN;
        mlb[q0 + wave * 32 + l31]      = m_run;
        mlb[NN + q0 + wave * 32 + l31] = l_run;
    }

    // Osh aliases Ks+Vt: all waves are done reading tiles (loop-end barrier).
    #pragma unroll
    for (int dt = 0; dt < 4; ++dt)
        #pragma unroll
        for (int h = 0; h < 4; ++h) {
            half4_t v;
            #pragma unroll
            for (int i = 0; i < 4; ++i) v[i] = (_Float16)o[dt][4 * h + i];
            // d = dt*32 + 8h + 4*l5 + i
            *(half4_t*)(Osh + (wave * 32 + l31) * 136 + dt * 32 + 8 * h + 4 * l5) = v;
        }
    __syncthreads();
    _Float16* Ob = Opart + ((size_t)(b * KS + sp) * NN + q0) * MID;
    #pragma unroll
    for (int it = 0; it < 8; ++it) {
        int c = it * 256 + t;           // 2048 half8-chunks: 128 q-rows x 16
        int q = c >> 4, g = c & 15;
        *(half8_t*)(Ob + (size_t)q * MID + g * 8) =
            *(const half8_t*)(Osh + q * 136 + g * 8);
    }
}

// ---------------------------------------------------------------------------
// Combine the KS partials: attnW = sum_s O_s*exp(m_s-m) / sum_s l_s*exp(m_s-m).
// Opart f16 lives in d_out; result written as f16 to ws attnW.
// grid (NN/32, BB), block 256: thread owns (q, 16 d-cols).
// ---------------------------------------------------------------------------
__global__ __launch_bounds__(256, 4) void comb_kernel(
    const _Float16* __restrict__ Opart, const float* __restrict__ MLg,
    _Float16* __restrict__ attnW)
{
    const int t  = threadIdx.x;
    const int b  = blockIdx.y;
    const int q  = blockIdx.x * 32 + (t >> 3);
    const int dg = (t & 7) * 16;

    float mv[KS], lv[KS];
    float m_g = -3.0e38f;
    #pragma unroll
    for (int s = 0; s < KS; ++s) {
        const float* mlb = MLg + ((size_t)(b * KS + s) * 2) * NN;
        mv[s] = mlb[q];
        lv[s] = mlb[NN + q];
        m_g = fmaxf(m_g, mv[s]);
    }
    float lg = 0.f, w[KS];
    #pragma unroll
    for (int s = 0; s < KS; ++s) { w[s] = __expf(mv[s] - m_g); lg += lv[s] * w[s]; }
    const float inv = 1.0f / lg;

    float acc[16];
    #pragma unroll
    for (int j = 0; j < 16; ++j) acc[j] = 0.f;
    #pragma unroll
    for (int s = 0; s < KS; ++s) {
        const half8_t* Op = (const half8_t*)(Opart + ((size_t)(b * KS + s) * NN + q) * MID + dg);
        half8_t v0 = Op[0], v1 = Op[1];
        #pragma unroll
        for (int j = 0; j < 8; ++j) {
            acc[j]     += (float)v0[j] * w[s];
            acc[8 + j] += (float)v1[j] * w[s];
        }
    }
    half8_t h0, h1;
    #pragma unroll
    for (int j = 0; j < 8; ++j) {
        h0[j] = (_Float16)(acc[j] * inv);
        h1[j] = (_Float16)(acc[8 + j] * inv);
    }
    half8_t* Ow = (half8_t*)(attnW + ((size_t)b * NN + q) * MID + dg);
    Ow[0] = h0; Ow[1] = h1;
}

// ---------------------------------------------------------------------------
// Epilogue: out[b][c][n] = x + w4 @ attn^T + b4. grid (NN/64, BB), block 256.
// attnW is f16 [b][n][128]; converted to f32 while staging to LDS.
// ---------------------------------------------------------------------------
__global__ __launch_bounds__(256, 2) void epi_kernel(
    const _Float16* __restrict__ attnW, const float* __restrict__ w4,
    const float* __restrict__ b4, const float* __restrict__ x,
    float* __restrict__ out)
{
    const int t  = threadIdx.x;
    const int n0 = blockIdx.x * 64;
    const int b  = blockIdx.y;

    __shared__ float as[64 * 132];
    for (int r = t; r < 64 * 16; r += 256) {
        int q = r >> 4, g = r & 15;
        half8_t v = *(const half8_t*)(attnW + ((size_t)b * NN + n0 + q) * MID + g * 8);
        float* dst = &as[q * 132 + g * 8];
        #pragma unroll
        for (int j = 0; j < 8; ++j) dst[j] = (float)v[j];
    }
    __syncthreads();

    const int n4 = (t & 15) << 2;
    const int c0 = (t >> 4) << 4;
    float4 accE[16];
    #pragma unroll
    for (int k = 0; k < 16; ++k) accE[k] = make_float4(0.f, 0.f, 0.f, 0.f);

    for (int ms = 0; ms < 32; ++ms) {
        float4 av[4];
        #pragma unroll
        for (int i = 0; i < 4; ++i)
            av[i] = *(const float4*)&as[(n4 + i) * 132 + (ms << 2)];
        #pragma unroll
        for (int k = 0; k < 16; ++k) {
            float4 wq = *(const float4*)(w4 + (size_t)(c0 + k) * MID + (ms << 2));
            accE[k].x += dot4(av[0], wq);
            accE[k].y += dot4(av[1], wq);
            accE[k].z += dot4(av[2], wq);
            accE[k].w += dot4(av[3], wq);
        }
    }

    #pragma unroll
    for (int k = 0; k < 16; ++k) {
        const int c = c0 + k;
        const float bv = b4[c];
        const size_t off = ((size_t)b * CC + c) * NN + n0 + n4;
        float4 xr = *(const float4*)(x + off);
        float4 r;
        r.x = accE[k].x + bv + xr.x;
        r.y = accE[k].y + bv + xr.y;
        r.z = accE[k].z + bv + xr.z;
        r.w = accE[k].w + bv + xr.w;
        *(float4*)(out + off) = r;
    }
}

extern "C" void kernel_launch(void* const* d_in, const int* in_sizes, int n_in,
                              void* d_out, int out_size, void* d_ws, size_t ws_size,
                              hipStream_t stream)
{
    const float* x  = (const float*)d_in[0];
    const float* w1 = (const float*)d_in[1];
    const float* b1 = (const float*)d_in[2];
    const float* w2 = (const float*)d_in[3];
    const float* b2 = (const float*)d_in[4];
    const float* w3 = (const float*)d_in[5];
    const float* b3 = (const float*)d_in[6];
    const float* w4 = (const float*)d_in[7];
    const float* b4 = (const float*)d_in[8];
    float* out = (float*)d_out;

    // ws: Qg f16 [B][N][128] | Kg f16 [B][N][128] | VtG f16 [B][128][N]
    //   | attnW f16 [B][N][128] | MLg f32 [B][KS][2][N]   (13.25 MB total)
    // Opart f16 [B][KS][N][128] aliases d_out (KS=4: exactly out_size).
    _Float16* Qg    = (_Float16*)d_ws;
    _Float16* Kg    = Qg + (size_t)BB * NN * MID;
    _Float16* VtG   = Kg + (size_t)BB * NN * MID;
    _Float16* attnW = VtG + (size_t)BB * NN * MID;
    float* MLg      = (float*)(attnW + (size_t)BB * NN * MID);
    _Float16* Opart = (_Float16*)d_out;

    proj_kernel<<<dim3(NN / 64, 3, BB), 256, 0, stream>>>(x, w1, b1, w2, b2, w3, b3, Qg, Kg, VtG);
    attn_kernel<<<dim3(NN / QB, KS, BB), 256, 0, stream>>>(Qg, Kg, VtG, Opart, MLg);
    comb_kernel<<<dim3(NN / 32, BB), 256, 0, stream>>>(Opart, MLg, attnW);
    epi_kernel<<<dim3(NN / 64, BB), 256, 0, stream>>>(attnW, w4, b4, x, out);
}

// Round 6
// 301.368 us; speedup vs baseline: 1.3418x; 1.0903x over previous
//
#include <hip/hip_runtime.h>

// NonLocalBlock: B=2, C=256, N=D*H*W=6272, mid=128.
// R6 = R5 (q-split 4-wave, KS=4 flash-decode) + in-register softmax->PV:
//  - P never touches LDS: cvt_pkrtz packs p-pairs to f16; permlane32_swap
//    builds the PV B-frags (for slice ks: (w0,w2)=swap(u0[2ks],u0[2ks+1]),
//    (w1,w3)=swap(u1[2ks],u1[2ks+1])). Removes 8 ds_write + lgkm drain +
//    4 ds_read_b128 per tile from the serial path; LDS 52224 -> 34816 B.
//  - exp2 folding: proj scales Q by log2(e); exp sites use exp2f (bare
//    v_exp_f32); m,l in log2 domain; comb weights use exp2f.
//  - unchanged: KS=4 partial f16 O in d_out, (m,l)->MLg, comb -> f16 attnW,
//    f16 epi, defer-max THR=0, 136/68 padded K/V strides (2-way = free).
// ws: Qg f16 | Kg f16 | VtG f16 | attnW f16 | MLg f32 = 13.25 MB.

#define BB  2
#define CC  256
#define NN  6272
#define MID 128
#define KS  4
#define QB  128
#define NT  (NN / 64)
#define LOG2E 1.4426950408889634f

typedef _Float16 half2_t __attribute__((ext_vector_type(2)));
typedef _Float16 half4_t __attribute__((ext_vector_type(4)));
typedef _Float16 half8_t __attribute__((ext_vector_type(8)));
typedef float    floatx16 __attribute__((ext_vector_type(16)));
typedef int      i32x2 __attribute__((ext_vector_type(2)));
typedef unsigned u32x4 __attribute__((ext_vector_type(4)));

__device__ __forceinline__ void fma4(float4& a, const float4 v, const float s) {
    a.x += v.x * s; a.y += v.y * s; a.z += v.z * s; a.w += v.w * s;
}
__device__ __forceinline__ float dot4(const float4 a, const float4 b) {
    return a.x * b.x + a.y * b.y + a.z * b.z + a.w * b.w;
}
__device__ __forceinline__ unsigned pkrtz(float a, float b) {
    return __builtin_bit_cast(unsigned, __builtin_amdgcn_cvt_pkrtz(a, b));
}

// ---------------------------------------------------------------------------
// Projection: e_pj[n][m] = dot(w_pj[m,:], x[b,:,n]) + bias.
// pj 0 -> Qg f16 [b][n][128] (PRE-SCALED by log2e); pj 1 -> Kg f16 [b][n][128];
// pj 2 -> VtG f16 [b][128][n]. grid (NN/64, 3, BB), block 256.
// ---------------------------------------------------------------------------
__global__ __launch_bounds__(256, 2) void proj_kernel(
    const float* __restrict__ x,
    const float* __restrict__ w1, const float* __restrict__ bi1,
    const float* __restrict__ w2, const float* __restrict__ bi2,
    const float* __restrict__ w3, const float* __restrict__ bi3,
    _Float16* __restrict__ Qg, _Float16* __restrict__ Kg, _Float16* __restrict__ VtG)
{
    const int t  = threadIdx.x;
    const int n0 = blockIdx.x * 64;
    const int pj = blockIdx.y;
    const int b  = blockIdx.z;
    const float* w  = (pj == 0) ? w1 : (pj == 1) ? w2 : w3;
    const float* bi = (pj == 0) ? bi1 : (pj == 1) ? bi2 : bi3;
    const float qs  = (pj == 0) ? LOG2E : 1.0f;

    __shared__ float xs[CC * 68];
    {
        const float* xb = x + (size_t)b * CC * NN;
        for (int r = t; r < CC * 16; r += 256) {
            int c = r >> 4, j = (r & 15) << 2;
            float4 v = *(const float4*)(xb + (size_t)c * NN + n0 + j);
            *(float4*)&xs[c * 68 + j] = v;
        }
    }
    __syncthreads();

    const int n4 = (t & 15) << 2;   // 4 consecutive n per thread
    const int m0 = (t >> 4) << 3;   // 8 m-rows per thread
    float4 acc4[8];
    #pragma unroll
    for (int k = 0; k < 8; ++k) acc4[k] = make_float4(0.f, 0.f, 0.f, 0.f);

    for (int cc = 0; cc < CC; cc += 4) {
        float4 xv[4];
        #pragma unroll
        for (int u = 0; u < 4; ++u)
            xv[u] = *(const float4*)&xs[(cc + u) * 68 + n4];
        #pragma unroll
        for (int k = 0; k < 8; ++k) {
            float4 wq = *(const float4*)(w + (size_t)(m0 + k) * CC + cc);
            fma4(acc4[k], xv[0], wq.x);
            fma4(acc4[k], xv[1], wq.y);
            fma4(acc4[k], xv[2], wq.z);
            fma4(acc4[k], xv[3], wq.w);
        }
    }

    const float* af = (const float*)acc4;   // af[k*4 + i], i = n-sub, k = m-sub
    float bb[8];
    #pragma unroll
    for (int k = 0; k < 8; ++k) bb[k] = bi[m0 + k];

    if (pj < 2) {
        _Float16* eo = ((pj == 0) ? Qg : Kg) + (size_t)b * NN * MID;
        #pragma unroll
        for (int i = 0; i < 4; ++i) {
            half8_t h;
            #pragma unroll
            for (int k = 0; k < 8; ++k) h[k] = (_Float16)((af[k * 4 + i] + bb[k]) * qs);
            *(half8_t*)(eo + (size_t)(n0 + n4 + i) * MID + m0) = h;
        }
    } else {
        _Float16* eo = VtG + (size_t)b * MID * NN;
        #pragma unroll
        for (int k = 0; k < 8; ++k) {
            half4_t h;
            #pragma unroll
            for (int i = 0; i < 4; ++i) h[i] = (_Float16)(af[k * 4 + i] + bb[k]);
            *(half4_t*)(eo + (size_t)(m0 + k) * NN + n0 + n4) = h;
        }
    }
}

// ---------------------------------------------------------------------------
// Flash attention partial, f16 MFMA, q-split, in-register P. grid
// (NN/QB, KS, BB), block 256 (4 waves). Wave w owns q-rows [q0+w*32, +32);
// waves share the staged K/V tile (64 keys). Scores are in log2 domain
// (Q pre-scaled); softmax uses exp2f. P stays in registers: pack pairs with
// cvt_pkrtz -> u0[G],u1[G] (G = 4*strip+g, k' = 8G + 4*l5 + {0..3}),
// PV B-frag for slice ks via 2 permlane32_swap.
// S^T strip: col q = lane&31, row k' = (reg&3)+8*(reg>>2)+4*(lane>>5).
// LDS (34816 B): Ks [64][136] h (17408) | Vt [128][68] h (17408).
// Osh [128][136] h aliases all of it for the store transpose.
// ---------------------------------------------------------------------------
__global__ __launch_bounds__(256, 2) void attn_kernel(
    const _Float16* __restrict__ Qg, const _Float16* __restrict__ Kg,
    const _Float16* __restrict__ VtG, _Float16* __restrict__ Opart,
    float* __restrict__ MLg)
{
    const int t    = threadIdx.x;
    const int lane = t & 63;
    const int wave = t >> 6;        // q-strip owner (0..3)
    const int l31  = lane & 31;
    const int l5   = lane >> 5;
    const int q0   = blockIdx.x * QB;
    const int sp   = blockIdx.y;
    const int b    = blockIdx.z;
    const int kt0  = (NT * sp) / KS;
    const int kt1  = (NT * (sp + 1)) / KS;

    __shared__ __align__(16) char lds[34816];
    _Float16* Ks  = (_Float16*)lds;               // 64*136 halfs
    _Float16* Vt  = (_Float16*)(lds + 17408);     // 128*68 halfs
    _Float16* Osh = (_Float16*)lds;               // [128][136] h alias

    const _Float16* Qb = Qg + ((size_t)b * NN + q0 + wave * 32) * MID;
    const _Float16* Kb = Kg + (size_t)b * NN * MID;
    const _Float16* Vb = VtG + (size_t)b * MID * NN;

    // Q B-frags: loop-invariant, pinned in registers (wave's own 32 q-rows).
    half8_t qf[8];
    #pragma unroll
    for (int ds = 0; ds < 8; ++ds)
        qf[ds] = *(const half8_t*)(Qb + (size_t)l31 * MID + ds * 16 + l5 * 8);

    floatx16 o[4];
    #pragma unroll
    for (int dt = 0; dt < 4; ++dt)
        #pragma unroll
        for (int j = 0; j < 16; ++j) o[dt][j] = 0.f;
    float m_run = -3.0e38f, l_run = 0.f;   // m in log2 domain

    for (int kt = kt0; kt < kt1; ++kt) {
        const int nk = kt * 64;
        // ---- stage K tile [64][136] and V^T tile [128][68], 256 threads ----
        #pragma unroll
        for (int it = 0; it < 4; ++it) {
            int c = it * 256 + t;
            int r = c >> 4, off = (c & 15) * 8;
            *(half8_t*)(Ks + r * 136 + off) =
                *(const half8_t*)(Kb + (size_t)(nk + r) * MID + off);
        }
        #pragma unroll
        for (int it = 0; it < 4; ++it) {
            int c = it * 256 + t;
            int d = c >> 3, off = (c & 7) * 8;
            *(half8_t*)(Vt + d * 68 + off) =
                *(const half8_t*)(Vb + (size_t)d * NN + nk + off);
        }
        __syncthreads();

        // ---- S^T strips: s0 = K[0:32].Q^T, s1 = K[32:64].Q^T (log2 domain) ----
        floatx16 s0, s1;
        #pragma unroll
        for (int j = 0; j < 16; ++j) { s0[j] = 0.f; s1[j] = 0.f; }
        const _Float16* krow0 = Ks + l31 * 136 + l5 * 8;
        const _Float16* krow1 = Ks + (32 + l31) * 136 + l5 * 8;
        #pragma unroll
        for (int ds = 0; ds < 8; ++ds) {
            s0 = __builtin_amdgcn_mfma_f32_32x32x16_f16(
                     *(const half8_t*)(krow0 + ds * 16), qf[ds], s0, 0, 0, 0);
            s1 = __builtin_amdgcn_mfma_f32_32x32x16_f16(
                     *(const half8_t*)(krow1 + ds * 16), qf[ds], s1, 0, 0, 0);
        }

        // ---- online softmax over 64 k' (lane: one q col, 32 of 64 rows) ----
        float tmax = fmaxf(s0[0], s1[0]);
        #pragma unroll
        for (int j = 1; j < 16; ++j) tmax = fmaxf(tmax, fmaxf(s0[j], s1[j]));
        tmax = fmaxf(tmax, __shfl_xor(tmax, 32));

        // defer-max (THR=0): skip rescale when no lane's max grew (exact).
        if (!__all(tmax <= m_run)) {
            const float m_new = fmaxf(m_run, tmax);
            const float alpha = exp2f(m_run - m_new);
            m_run = m_new;
            l_run *= alpha;
            #pragma unroll
            for (int dt = 0; dt < 4; ++dt)
                #pragma unroll
                for (int j = 0; j < 16; ++j) o[dt][j] *= alpha;
        }

        // ---- P in registers: u0[G] = k' 8G+4*l5+{0,1}, u1[G] = +{2,3} ----
        float psum = 0.f;
        unsigned u0[8], u1[8];
        #pragma unroll
        for (int g = 0; g < 4; ++g) {
            float p0 = exp2f(s0[4 * g + 0] - m_run);
            float p1 = exp2f(s0[4 * g + 1] - m_run);
            float p2 = exp2f(s0[4 * g + 2] - m_run);
            float p3 = exp2f(s0[4 * g + 3] - m_run);
            psum += (p0 + p1) + (p2 + p3);
            u0[g] = pkrtz(p0, p1);
            u1[g] = pkrtz(p2, p3);
        }
        #pragma unroll
        for (int g = 0; g < 4; ++g) {
            float p0 = exp2f(s1[4 * g + 0] - m_run);
            float p1 = exp2f(s1[4 * g + 1] - m_run);
            float p2 = exp2f(s1[4 * g + 2] - m_run);
            float p3 = exp2f(s1[4 * g + 3] - m_run);
            psum += (p0 + p1) + (p2 + p3);
            u0[4 + g] = pkrtz(p0, p1);
            u1[4 + g] = pkrtz(p2, p3);
        }
        psum += __shfl_xor(psum, 32);
        l_run += psum;

        // ---- O^T += V^T . P^T, K = 64; B-frags built via permlane32_swap ----
        // For slice ks: rows k = 16ks + 8*l5 + {0..7}. (w0,w2)=swap(u0[2ks],
        // u0[2ks+1]); (w1,w3)=swap(u1[2ks],u1[2ks+1]); frag = [w0 w1 w2 w3].
        #pragma unroll
        for (int ks = 0; ks < 4; ++ks) {
            i32x2 rA = __builtin_amdgcn_permlane32_swap(
                           (int)u0[2 * ks], (int)u0[2 * ks + 1], false, false);
            i32x2 rB = __builtin_amdgcn_permlane32_swap(
                           (int)u1[2 * ks], (int)u1[2 * ks + 1], false, false);
            u32x4 pw;
            pw[0] = (unsigned)rA[0]; pw[1] = (unsigned)rB[0];
            pw[2] = (unsigned)rA[1]; pw[3] = (unsigned)rB[1];
            half8_t pf = __builtin_bit_cast(half8_t, pw);
            const _Float16* vcol = Vt + ks * 16 + l5 * 8;
            #pragma unroll
            for (int dt = 0; dt < 4; ++dt)
                o[dt] = __builtin_amdgcn_mfma_f32_32x32x16_f16(
                            *(const half8_t*)(vcol + (dt * 32 + l31) * 68), pf,
                            o[dt], 0, 0, 0);
        }
        __syncthreads();
    }

    // ---- per-row (m,l) out; transpose O via LDS; store UNNORMALIZED f16 ----
    if (l5 == 0) {
        float* mlb = MLg + ((size_t)(b * KS + sp) * 2) * NN;
        mlb[q0 + wave * 32 + l31]      = m_run;   // log2-domain max
        mlb[NN + q0 + wave * 32 + l31] = l_run;
    }

    // Osh aliases Ks+Vt: all waves are done reading tiles (loop-end barrier).
    #pragma unroll
    for (int dt = 0; dt < 4; ++dt)
        #pragma unroll
        for (int h = 0; h < 4; ++h) {
            half4_t v;
            #pragma unroll
            for (int i = 0; i < 4; ++i) v[i] = (_Float16)o[dt][4 * h + i];
            // d = dt*32 + 8h + 4*l5 + i
            *(half4_t*)(Osh + (wave * 32 + l31) * 136 + dt * 32 + 8 * h + 4 * l5) = v;
        }
    __syncthreads();
    _Float16* Ob = Opart + ((size_t)(b * KS + sp) * NN + q0) * MID;
    #pragma unroll
    for (int it = 0; it < 8; ++it) {
        int c = it * 256 + t;           // 2048 half8-chunks: 128 q-rows x 16
        int q = c >> 4, g = c & 15;
        *(half8_t*)(Ob + (size_t)q * MID + g * 8) =
            *(const half8_t*)(Osh + q * 136 + g * 8);
    }
}

// ---------------------------------------------------------------------------
// Combine the KS partials: attnW = sum_s O_s*2^(m_s-m) / sum_s l_s*2^(m_s-m).
// Opart f16 lives in d_out; result written as f16 to ws attnW.
// grid (NN/32, BB), block 256: thread owns (q, 16 d-cols).
// ---------------------------------------------------------------------------
__global__ __launch_bounds__(256, 4) void comb_kernel(
    const _Float16* __restrict__ Opart, const float* __restrict__ MLg,
    _Float16* __restrict__ attnW)
{
    const int t  = threadIdx.x;
    const int b  = blockIdx.y;
    const int q  = blockIdx.x * 32 + (t >> 3);
    const int dg = (t & 7) * 16;

    float mv[KS], lv[KS];
    float m_g = -3.0e38f;
    #pragma unroll
    for (int s = 0; s < KS; ++s) {
        const float* mlb = MLg + ((size_t)(b * KS + s) * 2) * NN;
        mv[s] = mlb[q];
        lv[s] = mlb[NN + q];
        m_g = fmaxf(m_g, mv[s]);
    }
    float lg = 0.f, w[KS];
    #pragma unroll
    for (int s = 0; s < KS; ++s) { w[s] = exp2f(mv[s] - m_g); lg += lv[s] * w[s]; }
    const float inv = 1.0f / lg;

    float acc[16];
    #pragma unroll
    for (int j = 0; j < 16; ++j) acc[j] = 0.f;
    #pragma unroll
    for (int s = 0; s < KS; ++s) {
        const half8_t* Op = (const half8_t*)(Opart + ((size_t)(b * KS + s) * NN + q) * MID + dg);
        half8_t v0 = Op[0], v1 = Op[1];
        #pragma unroll
        for (int j = 0; j < 8; ++j) {
            acc[j]     += (float)v0[j] * w[s];
            acc[8 + j] += (float)v1[j] * w[s];
        }
    }
    half8_t h0, h1;
    #pragma unroll
    for (int j = 0; j < 8; ++j) {
        h0[j] = (_Float16)(acc[j] * inv);
        h1[j] = (_Float16)(acc[8 + j] * inv);
    }
    half8_t* Ow = (half8_t*)(attnW + ((size_t)b * NN + q) * MID + dg);
    Ow[0] = h0; Ow[1] = h1;
}

// ---------------------------------------------------------------------------
// Epilogue: out[b][c][n] = x + w4 @ attn^T + b4. grid (NN/64, BB), block 256.
// attnW is f16 [b][n][128]; converted to f32 while staging to LDS.
// ---------------------------------------------------------------------------
__global__ __launch_bounds__(256, 2) void epi_kernel(
    const _Float16* __restrict__ attnW, const float* __restrict__ w4,
    const float* __restrict__ b4, const float* __restrict__ x,
    float* __restrict__ out)
{
    const int t  = threadIdx.x;
    const int n0 = blockIdx.x * 64;
    const int b  = blockIdx.y;

    __shared__ float as[64 * 132];
    for (int r = t; r < 64 * 16; r += 256) {
        int q = r >> 4, g = r & 15;
        half8_t v = *(const half8_t*)(attnW + ((size_t)b * NN + n0 + q) * MID + g * 8);
        float* dst = &as[q * 132 + g * 8];
        #pragma unroll
        for (int j = 0; j < 8; ++j) dst[j] = (float)v[j];
    }
    __syncthreads();

    const int n4 = (t & 15) << 2;
    const int c0 = (t >> 4) << 4;
    float4 accE[16];
    #pragma unroll
    for (int k = 0; k < 16; ++k) accE[k] = make_float4(0.f, 0.f, 0.f, 0.f);

    for (int ms = 0; ms < 32; ++ms) {
        float4 av[4];
        #pragma unroll
        for (int i = 0; i < 4; ++i)
            av[i] = *(const float4*)&as[(n4 + i) * 132 + (ms << 2)];
        #pragma unroll
        for (int k = 0; k < 16; ++k) {
            float4 wq = *(const float4*)(w4 + (size_t)(c0 + k) * MID + (ms << 2));
            accE[k].x += dot4(av[0], wq);
            accE[k].y += dot4(av[1], wq);
            accE[k].z += dot4(av[2], wq);
            accE[k].w += dot4(av[3], wq);
        }
    }

    #pragma unroll
    for (int k = 0; k < 16; ++k) {
        const int c = c0 + k;
        const float bv = b4[c];
        const size_t off = ((size_t)b * CC + c) * NN + n0 + n4;
        float4 xr = *(const float4*)(x + off);
        float4 r;
        r.x = accE[k].x + bv + xr.x;
        r.y = accE[k].y + bv + xr.y;
        r.z = accE[k].z + bv + xr.z;
        r.w = accE[k].w + bv + xr.w;
        *(float4*)(out + off) = r;
    }
}

extern "C" void kernel_launch(void* const* d_in, const int* in_sizes, int n_in,
                              void* d_out, int out_size, void* d_ws, size_t ws_size,
                              hipStream_t stream)
{
    const float* x  = (const float*)d_in[0];
    const float* w1 = (const float*)d_in[1];
    const float* b1 = (const float*)d_in[2];
    const float* w2 = (const float*)d_in[3];
    const float* b2 = (const float*)d_in[4];
    const float* w3 = (const float*)d_in[5];
    const float* b3 = (const float*)d_in[6];
    const float* w4 = (const float*)d_in[7];
    const float* b4 = (const float*)d_in[8];
    float* out = (float*)d_out;

    // ws: Qg f16 [B][N][128] | Kg f16 [B][N][128] | VtG f16 [B][128][N]
    //   | attnW f16 [B][N][128] | MLg f32 [B][KS][2][N]   (13.25 MB total)
    // Opart f16 [B][KS][N][128] aliases d_out (KS=4: exactly out_size).
    _Float16* Qg    = (_Float16*)d_ws;
    _Float16* Kg    = Qg + (size_t)BB * NN * MID;
    _Float16* VtG   = Kg + (size_t)BB * NN * MID;
    _Float16* attnW = VtG + (size_t)BB * NN * MID;
    float* MLg      = (float*)(attnW + (size_t)BB * NN * MID);
    _Float16* Opart = (_Float16*)d_out;

    proj_kernel<<<dim3(NN / 64, 3, BB), 256, 0, stream>>>(x, w1, b1, w2, b2, w3, b3, Qg, Kg, VtG);
    attn_kernel<<<dim3(NN / QB, KS, BB), 256, 0, stream>>>(Qg, Kg, VtG, Opart, MLg);
    comb_kernel<<<dim3(NN / 32, BB), 256, 0, stream>>>(Opart, MLg, attnW);
    epi_kernel<<<dim3(NN / 64, BB), 256, 0, stream>>>(attnW, w4, b4, x, out);
}